// Round 7
// baseline (292.369 us; speedup 1.0000x reference)
//
#include <hip/hip_runtime.h>

#define N_PTS 1000000
#define H_DIM 200
#define W_DIM 70400
#define FILL_V -9999999.0f

typedef float v2f __attribute__((ext_vector_type(2)));

__device__ __forceinline__ v2f fma2(v2f a, v2f b, v2f c) {
    return __builtin_elementwise_fma(a, b, c);   // -> v_pk_fma_f32 on gfx950
}

// ---------------------------------------------------------------------------
// Kernel A v4 (R7): TWO points per thread + EXPLICIT register budget.
// R5 post-mortem: with default launch_bounds the allocator capped at 72 VGPR
// (no scratch traffic -> it REMATERIALIZED h1/h2 instead of spilling; VALU
// time 34->128us). The 2-pt hypothesis (halve per-point s_load weight
// stream, double fma ILP) was never actually tested. launch_bounds(256,4)
// grants ~128 VGPR -- live set needs ~115-130. Occupancy cap at 128 VGPR is
// 16 waves/CU, ABOVE the ~12 waves/CU rocprof shows today -> no loss.
// R6 post-mortem: cooperative fused kernel never launched (absmax 0.107 ==
// max|ref|, i.e. output stayed memset-zero) -> cooperative path abandoned.
// All per-point state in named, statically-indexed variables (rule #20).
// List entry: .x = value bits, .y = (point_index << 8) | row  (row<200<256).
// Last-write-wins scatter: point survives iff no LATER point hit (row,col).
// ---------------------------------------------------------------------------
__global__ void __launch_bounds__(256, 4) mlp_scatter_kernel(
    const float* __restrict__ input,        // [4][N]
    const int* __restrict__ tindex,         // [N][2] int32 (row, col)
    const float* __restrict__ w1, const float* __restrict__ b1,
    const float* __restrict__ w2, const float* __restrict__ b2,
    const float* __restrict__ w3, const float* __restrict__ b3,
    const float* __restrict__ w4, const float* __restrict__ b4,
    int* __restrict__ counts,               // [W]
    uint2* __restrict__ list,               // [W][maxk]
    int maxk)
{
    // empty-branch (reference: tensor_index[0,0] == -1 -> no scatter)
    if (tindex[0] == -1) return;

    const int t = blockIdx.x * 256 + threadIdx.x;
    const int i = t * 2;                    // point pair (i, i+1); N is even
    if (i >= N_PTS) return;

    // scatter-slot atomics issued first; latency hides under the MLP
    const int4 hw2 = ((const int4*)tindex)[t];   // (rowA, colA, rowB, colB)
    const int posA = atomicAdd(&counts[hw2.y], 1);
    const int posB = atomicAdd(&counts[hw2.w], 1);

    const v2f* __restrict__ w1v = (const v2f*)w1;   // rows of 4 = 2 v2f
    const v2f* __restrict__ w2v = (const v2f*)w2;   // rows of 18 = 9 v2f
    const v2f* __restrict__ w3v = (const v2f*)w3;   // rows of 36 = 18 v2f

    // input rows: 2 consecutive floats per row -> contiguous wave access
    const v2f xc0 = *(const v2f*)&input[0 * N_PTS + i];
    const v2f xc1 = *(const v2f*)&input[1 * N_PTS + i];
    const v2f xc2 = *(const v2f*)&input[2 * N_PTS + i];
    const v2f xc3 = *(const v2f*)&input[3 * N_PTS + i];
    const v2f xA01 = { xc0.x, xc1.x }, xA23 = { xc2.x, xc3.x };
    const v2f xB01 = { xc0.y, xc1.y }, xB23 = { xc2.y, xc3.y };

    // layer 1: 18 outputs, k packed; each weight fetch feeds BOTH points
    v2f h1a[9], h1b[9];
#pragma unroll
    for (int o = 0; o < 18; ++o) {
        const v2f wr0 = w1v[o * 2 + 0], wr1 = w1v[o * 2 + 1];
        v2f aA = { b1[o], 0.0f };
        v2f aB = aA;
        aA = fma2(wr0, xA01, aA); aA = fma2(wr1, xA23, aA);
        aB = fma2(wr0, xB01, aB); aB = fma2(wr1, xB23, aB);
        const float hA = fmaxf(aA.x + aA.y, 0.0f);
        const float hB = fmaxf(aB.x + aB.y, 0.0f);
        if (o & 1) { h1a[o >> 1].y = hA; h1b[o >> 1].y = hB; }
        else       { h1a[o >> 1].x = hA; h1b[o >> 1].x = hB; }
    }

    // layer 2: 36 outputs, k packed (18 -> 9 pairs)
    v2f h2a[18], h2b[18];
#pragma unroll
    for (int o = 0; o < 36; ++o) {
        v2f aA = { b2[o], 0.0f };
        v2f aB = aA;
#pragma unroll
        for (int q = 0; q < 9; ++q) {
            const v2f wq = w2v[o * 9 + q];
            aA = fma2(wq, h1a[q], aA);
            aB = fma2(wq, h1b[q], aB);
        }
        const float hA = fmaxf(aA.x + aA.y, 0.0f);
        const float hB = fmaxf(aB.x + aB.y, 0.0f);
        if (o & 1) { h2a[o >> 1].y = hA; h2b[o >> 1].y = hB; }
        else       { h2a[o >> 1].x = hA; h2b[o >> 1].x = hB; }
    }

    // layer 3 (k packed, 36 -> 18 pairs) with layer 4 fused
    float vA = b4[0], vB = vA;
#pragma unroll
    for (int o = 0; o < 36; ++o) {
        v2f aA = { b3[o], 0.0f };
        v2f aB = aA;
#pragma unroll
        for (int q = 0; q < 18; ++q) {
            const v2f wq = w3v[o * 18 + q];
            aA = fma2(wq, h2a[q], aA);
            aB = fma2(wq, h2b[q], aB);
        }
        const float w4o = w4[o];
        vA = fmaf(w4o, fmaxf(aA.x + aA.y, 0.0f), vA);
        vB = fmaf(w4o, fmaxf(aB.x + aB.y, 0.0f), vB);
    }

    if (posA < maxk) {   // never overflows statistically at maxk>=64
        uint2 e;
        e.x = __float_as_uint(vA);
        e.y = ((unsigned)i << 8) | (unsigned)hw2.x;
        list[(size_t)hw2.y * maxk + posA] = e;
    }
    if (posB < maxk) {
        uint2 e;
        e.x = __float_as_uint(vB);
        e.y = ((unsigned)(i + 1) << 8) | (unsigned)hw2.z;
        list[(size_t)hw2.w * maxk + posB] = e;
    }
}

// Wave-local LDS ordering: drain this wave's outstanding DS ops. "memory"
// clobber orders surrounding memory ops (consumers here are ds ops, so the
// clobber suffices; rule-#18 hazard applies only to reg-only consumers).
__device__ __forceinline__ void lds_wave_fence() {
    asm volatile("s_waitcnt lgkmcnt(0)" ::: "memory");
}

// ---------------------------------------------------------------------------
// Kernel B (exact R4-verified version): 32-bit dedup keys, native
// ds_max_u32, grid-stride 2200 blocks x 4 waves x 8 cols, barrier-free.
// Key = (i<<8)|row (28 bits) = e.y; winner per row = max key; lane
// re-identifies via tbl[row]==e.y and contributes its own e.x.
// ---------------------------------------------------------------------------
__global__ void __launch_bounds__(256) colmax_kernel(
    const int* __restrict__ tindex,
    const int* __restrict__ counts,
    const uint2* __restrict__ list,
    float* __restrict__ out,
    int maxk)
{
    __shared__ unsigned rowwin[4][200];
    const int lane = threadIdx.x;        // 0..63
    const int y    = threadIdx.y;        // 0..3
    unsigned* tbl = rowwin[y];

    const bool empty = (tindex[0] == -1);

    if (blockIdx.x == 0 && lane == 0 && y == 0)
        out[W_DIM] = empty ? 0.0f : 1.0f;    // flag output

    // zero the full per-wave table once (rows 0..199)
    tbl[lane]       = 0u;
    tbl[lane + 64]  = 0u;
    tbl[lane + 128] = 0u;
    if (lane < 8) tbl[lane + 192] = 0u;
    lds_wave_fence();

    const int step = gridDim.x * 4;
    for (int w = blockIdx.x * 4 + y; w < W_DIM; w += step) {
        int c = 0;
        if (!empty) {
            c = counts[w];
            if (c > maxk) c = maxk;
        }

        uint2 e = make_uint2(0u, 0u);
        const bool have = (lane < c);
        float v = FILL_V;
        if (have) {
            e = list[(size_t)w * maxk + lane];
            atomicMax(&tbl[e.y & 0xFFu], e.y);   // native ds_max_u32
        }
        lds_wave_fence();                 // all lanes' maxes visible
        if (have) {
            if (tbl[e.y & 0xFFu] == e.y)  // unique keys -> exactly one winner/row
                v = __uint_as_float(e.x);
            tbl[e.y & 0xFFu] = 0u;        // re-zero only dirtied rows
        }
        lds_wave_fence();                 // zeros land before next column

#pragma unroll
        for (int off = 32; off > 0; off >>= 1)
            v = fmaxf(v, __shfl_down(v, off, 64));

        if (lane == 0) out[w] = v;
    }
}

extern "C" void kernel_launch(void* const* d_in, const int* in_sizes, int n_in,
                              void* d_out, int out_size, void* d_ws, size_t ws_size,
                              hipStream_t stream) {
    const float* input  = (const float*)d_in[0];
    const int*   tindex = (const int*)d_in[1];   // int32 on device
    const float* w1 = (const float*)d_in[2];
    const float* b1 = (const float*)d_in[3];
    const float* w2 = (const float*)d_in[4];
    const float* b2 = (const float*)d_in[5];
    const float* w3 = (const float*)d_in[6];
    const float* b3 = (const float*)d_in[7];
    const float* w4 = (const float*)d_in[8];
    const float* b4 = (const float*)d_in[9];
    float* out = (float*)d_out;

    // workspace: counts [70400 int] | list [70400][maxk] uint2
    int*   counts = (int*)d_ws;
    uint2* list   = (uint2*)((char*)d_ws + (size_t)W_DIM * sizeof(int));

    size_t avail = (ws_size > (size_t)W_DIM * sizeof(int))
                       ? ws_size - (size_t)W_DIM * sizeof(int) : 0;
    int maxk = (int)(avail / ((size_t)W_DIM * sizeof(uint2)));
    if (maxk > 64) maxk = 64;
    if (maxk < 1)  maxk = 1;

    (void)hipMemsetAsync(counts, 0, (size_t)W_DIM * sizeof(int), stream);

    // 2 points per thread: 500000 threads -> 1954 blocks
    mlp_scatter_kernel<<<(N_PTS / 2 + 255) / 256, 256, 0, stream>>>(
        input, tindex, w1, b1, w2, b2, w3, b3, w4, b4, counts, list, maxk);

    // grid-stride: 2200 blocks x 4 waves x 8 columns = 70400 exactly
    colmax_kernel<<<2200, dim3(64, 4), 0, stream>>>(
        tindex, counts, list, out, maxk);
}

// Round 8
// 174.459 us; speedup vs baseline: 1.6759x; 1.6759x over previous
//
#include <hip/hip_runtime.h>

#define N_PTS 1000000
#define H_DIM 200
#define W_DIM 70400
#define FILL_V -9999999.0f

typedef float v2f __attribute__((ext_vector_type(2)));

__device__ __forceinline__ v2f fma2(v2f a, v2f b, v2f c) {
    return __builtin_elementwise_fma(a, b, c);   // -> v_pk_fma_f32 on gfx950
}

// ---------------------------------------------------------------------------
// Kernel A v5 (R8): proven 1-pt body, 512-THREAD BLOCKS.
// R5/R7 post-mortem: 2-pt per thread is dead twice over (default bounds ->
// remat, 68% VALU, 187us; launch_bounds(256,4) -> 56 VGPR + scratch spill,
// FETCH 12->59MB, WRITE 62->122MB, 200us). Reverted to the 60-VGPR 1-pt body.
// R8 experiment: every variant so far used 256-thread blocks and EVERY one
// reported ~38% occupancy (~12 waves/CU) despite 60 VGPR / 0 LDS allowing
// 32. Hypothesis: per-CU workgroup-slot cap (~3 wg/CU) is the limiter, and
// 3 waves/SIMD cannot hide the ~134 s_load weight stream per point-body
// (VALUBusy stuck at 40%). 512-thread blocks (8 waves) at 4 blocks/CU force
// 32 waves/CU. VGPR budget: 8 waves x 64 x 60 = 30720/block, x4 = 122880 <
// 131072 regsPerBlock -- fits. Grid 1954 blocks = 7.6/CU, smooth tail.
// Dispatch accounting (R7): iteration carries ~13 harness dispatches
// (~60-80us fixed floor). mlp is the only substantive lever left.
// List entry: .x = value bits, .y = (point_index << 8) | row  (row<200<256).
// Last-write-wins scatter: point survives iff no LATER point hit (row,col).
// ---------------------------------------------------------------------------
__global__ void __launch_bounds__(512) mlp_scatter_kernel(
    const float* __restrict__ input,        // [4][N]
    const int* __restrict__ tindex,         // [N][2] int32 (row, col)
    const float* __restrict__ w1, const float* __restrict__ b1,
    const float* __restrict__ w2, const float* __restrict__ b2,
    const float* __restrict__ w3, const float* __restrict__ b3,
    const float* __restrict__ w4, const float* __restrict__ b4,
    int* __restrict__ counts,               // [W]
    uint2* __restrict__ list,               // [W][maxk]
    int maxk)
{
    // empty-branch (reference: tensor_index[0,0] == -1 -> no scatter)
    if (tindex[0] == -1) return;

    const int i = blockIdx.x * 512 + threadIdx.x;
    if (i >= N_PTS) return;

    // scatter-slot atomic issued first; latency hides under the MLP
    const int2 hw = ((const int2*)tindex)[i];   // (row, col)
    const int pos = atomicAdd(&counts[hw.y], 1);

    const v2f* __restrict__ w1v = (const v2f*)w1;   // rows of 4 = 2 v2f
    const v2f* __restrict__ w2v = (const v2f*)w2;   // rows of 18 = 9 v2f
    const v2f* __restrict__ w3v = (const v2f*)w3;   // rows of 36 = 18 v2f

    const v2f x01 = { input[0 * N_PTS + i], input[1 * N_PTS + i] };
    const v2f x23 = { input[2 * N_PTS + i], input[3 * N_PTS + i] };

    // layer 1: 18 outputs, k packed (4 -> 2 pairs)
    v2f h1v[9];
#pragma unroll
    for (int o = 0; o < 18; ++o) {
        v2f acc = { b1[o], 0.0f };               // bias rides in .x
        acc = fma2(w1v[o * 2 + 0], x01, acc);
        acc = fma2(w1v[o * 2 + 1], x23, acc);
        const float h = fmaxf(acc.x + acc.y, 0.0f);
        if (o & 1) h1v[o >> 1].y = h; else h1v[o >> 1].x = h;
    }

    // layer 2: 36 outputs, k packed (18 -> 9 pairs)
    v2f h2v[18];
#pragma unroll
    for (int o = 0; o < 36; ++o) {
        v2f acc = { b2[o], 0.0f };
#pragma unroll
        for (int q = 0; q < 9; ++q)
            acc = fma2(w2v[o * 9 + q], h1v[q], acc);
        const float h = fmaxf(acc.x + acc.y, 0.0f);
        if (o & 1) h2v[o >> 1].y = h; else h2v[o >> 1].x = h;
    }

    // layer 3 (k packed, 36 -> 18 pairs) with layer 4 fused
    float v = b4[0];
#pragma unroll
    for (int o = 0; o < 36; ++o) {
        v2f acc = { b3[o], 0.0f };
#pragma unroll
        for (int q = 0; q < 18; ++q)
            acc = fma2(w3v[o * 18 + q], h2v[q], acc);
        v = fmaf(w4[o], fmaxf(acc.x + acc.y, 0.0f), v);
    }

    if (pos < maxk) {   // never overflows statistically at maxk>=64 (mean 14.2/col)
        uint2 e;
        e.x = __float_as_uint(v);
        e.y = ((unsigned)i << 8) | (unsigned)hw.x;
        list[(size_t)hw.y * maxk + pos] = e;
    }
}

// Wave-local LDS ordering: drain this wave's outstanding DS ops. "memory"
// clobber orders surrounding memory ops (consumers here are ds ops, so the
// clobber suffices; rule-#18 hazard applies only to reg-only consumers).
__device__ __forceinline__ void lds_wave_fence() {
    asm volatile("s_waitcnt lgkmcnt(0)" ::: "memory");
}

// ---------------------------------------------------------------------------
// Kernel B (exact R4-verified version): 32-bit dedup keys, native
// ds_max_u32, grid-stride 2200 blocks x 4 waves x 8 cols, barrier-free.
// Key = (i<<8)|row (28 bits) = e.y; winner per row = max key; lane
// re-identifies via tbl[row]==e.y and contributes its own e.x.
// Latency model says this kernel is ~5-10us; the old "~80us colmax
// residual" was mostly the ~13 harness restore dispatches per iteration.
// ---------------------------------------------------------------------------
__global__ void __launch_bounds__(256) colmax_kernel(
    const int* __restrict__ tindex,
    const int* __restrict__ counts,
    const uint2* __restrict__ list,
    float* __restrict__ out,
    int maxk)
{
    __shared__ unsigned rowwin[4][200];
    const int lane = threadIdx.x;        // 0..63
    const int y    = threadIdx.y;        // 0..3
    unsigned* tbl = rowwin[y];

    const bool empty = (tindex[0] == -1);

    if (blockIdx.x == 0 && lane == 0 && y == 0)
        out[W_DIM] = empty ? 0.0f : 1.0f;    // flag output

    // zero the full per-wave table once (rows 0..199)
    tbl[lane]       = 0u;
    tbl[lane + 64]  = 0u;
    tbl[lane + 128] = 0u;
    if (lane < 8) tbl[lane + 192] = 0u;
    lds_wave_fence();

    const int step = gridDim.x * 4;
    for (int w = blockIdx.x * 4 + y; w < W_DIM; w += step) {
        int c = 0;
        if (!empty) {
            c = counts[w];
            if (c > maxk) c = maxk;
        }

        uint2 e = make_uint2(0u, 0u);
        const bool have = (lane < c);
        float v = FILL_V;
        if (have) {
            e = list[(size_t)w * maxk + lane];
            atomicMax(&tbl[e.y & 0xFFu], e.y);   // native ds_max_u32
        }
        lds_wave_fence();                 // all lanes' maxes visible
        if (have) {
            if (tbl[e.y & 0xFFu] == e.y)  // unique keys -> exactly one winner/row
                v = __uint_as_float(e.x);
            tbl[e.y & 0xFFu] = 0u;        // re-zero only dirtied rows
        }
        lds_wave_fence();                 // zeros land before next column

#pragma unroll
        for (int off = 32; off > 0; off >>= 1)
            v = fmaxf(v, __shfl_down(v, off, 64));

        if (lane == 0) out[w] = v;
    }
}

extern "C" void kernel_launch(void* const* d_in, const int* in_sizes, int n_in,
                              void* d_out, int out_size, void* d_ws, size_t ws_size,
                              hipStream_t stream) {
    const float* input  = (const float*)d_in[0];
    const int*   tindex = (const int*)d_in[1];   // int32 on device
    const float* w1 = (const float*)d_in[2];
    const float* b1 = (const float*)d_in[3];
    const float* w2 = (const float*)d_in[4];
    const float* b2 = (const float*)d_in[5];
    const float* w3 = (const float*)d_in[6];
    const float* b3 = (const float*)d_in[7];
    const float* w4 = (const float*)d_in[8];
    const float* b4 = (const float*)d_in[9];
    float* out = (float*)d_out;

    // workspace: counts [70400 int] | list [70400][maxk] uint2
    int*   counts = (int*)d_ws;
    uint2* list   = (uint2*)((char*)d_ws + (size_t)W_DIM * sizeof(int));

    size_t avail = (ws_size > (size_t)W_DIM * sizeof(int))
                       ? ws_size - (size_t)W_DIM * sizeof(int) : 0;
    int maxk = (int)(avail / ((size_t)W_DIM * sizeof(uint2)));
    if (maxk > 64) maxk = 64;
    if (maxk < 1)  maxk = 1;

    (void)hipMemsetAsync(counts, 0, (size_t)W_DIM * sizeof(int), stream);

    // 512-thread blocks: 1954 blocks, 8 waves/block, 4 blocks/CU = 32 waves/CU
    mlp_scatter_kernel<<<(N_PTS + 511) / 512, 512, 0, stream>>>(
        input, tindex, w1, b1, w2, b2, w3, b3, w4, b4, counts, list, maxk);

    // grid-stride: 2200 blocks x 4 waves x 8 columns = 70400 exactly
    colmax_kernel<<<2200, dim3(64, 4), 0, stream>>>(
        tindex, counts, list, out, maxk);
}

// Round 9
// 162.305 us; speedup vs baseline: 1.8014x; 1.0749x over previous
//
#include <hip/hip_runtime.h>

#define N_PTS 1000000
#define H_DIM 200
#define W_DIM 70400
#define FILL_V -9999999.0f

// ws layout: counts[70400 int] | wpack[6656 bf16 = 13312 B] | list[70400][maxk] uint2
#define COUNTS_BYTES ((size_t)W_DIM * sizeof(int))
#define WPACK_ELEMS  6656
#define WPACK_BYTES  ((size_t)WPACK_ELEMS * 2)

typedef __attribute__((ext_vector_type(4))) float f32x4;
typedef __attribute__((ext_vector_type(8))) short bf16x8;

__device__ __forceinline__ unsigned bperm_u(unsigned src_lane, unsigned v) {
    return (unsigned)__builtin_amdgcn_ds_bpermute((int)(src_lane << 2), (int)v);
}
__device__ __forceinline__ unsigned cvt_pk_bf16(float lo, float hi) {
    unsigned d;
    asm("v_cvt_pk_bf16_f32 %0, %1, %2" : "=v"(d) : "v"(lo), "v"(hi));
    return d;
}
__device__ __forceinline__ bf16x8 mk_frag(unsigned d0, unsigned d1,
                                          unsigned d2, unsigned d3) {
    union { unsigned u[4]; bf16x8 s; } u;
    u.u[0] = d0; u.u[1] = d1; u.u[2] = d2; u.u[3] = d3;
    return u.s;
}

// ---------------------------------------------------------------------------
// Prep: pack weights as bf16 MFMA A-fragments, biases FOLDED as extra K-row.
// Effective matrices (row-padded to 16, K-padded to 32/64):
//   A1 = W1eff[32][32]: rows<18: [w1 | b1@k=4  | 0]      frags 0..1   (mt)
//   A2 = W2eff[48][32]: rows<36: [w2 | b2@k=18 | 0]      frags 2..4   (mt)
//   A3 = W3eff[48][64]: rows<36: [w3 | b3@k=36 | 0]      frags 5..10  (mt*2+kt)
//   A4 = W4eff[16][64]: row0:    [w4 | b4@k=36 | 0]      frags 11..12 (kt)
// Fragment layout (16x16x32 bf16 A): lane l holds row=(l&15), k=(l>>4)*8+j,
// j ascending through the short8 (k-even in low half of each dword) --
// consistent with the m156/m162-verified transpose-read mapping.
// ---------------------------------------------------------------------------
__global__ void __launch_bounds__(256) pack_weights_kernel(
    const float* __restrict__ w1, const float* __restrict__ b1,
    const float* __restrict__ w2, const float* __restrict__ b2,
    const float* __restrict__ w3, const float* __restrict__ b3,
    const float* __restrict__ w4, const float* __restrict__ b4,
    unsigned short* __restrict__ wp)
{
    for (int idx = threadIdx.x; idx < WPACK_ELEMS; idx += 256) {
        const int rem  = idx & 511;
        const int lane = rem >> 3, j = rem & 7;
        const int c16 = lane & 15, g = lane >> 4;
        const int kloc = g * 8 + j;
        float v = 0.0f;
        if (idx < 1024) {                       // A1
            const int row = (idx >> 9) * 16 + c16, k = kloc;
            if (row < 18) v = (k < 4) ? w1[row * 4 + k] : (k == 4 ? b1[row] : 0.0f);
        } else if (idx < 2560) {                // A2
            const int row = ((idx - 1024) >> 9) * 16 + c16, k = kloc;
            if (row < 36) v = (k < 18) ? w2[row * 18 + k] : (k == 18 ? b2[row] : 0.0f);
        } else if (idx < 5632) {                // A3 [mt][kt]
            const int f = (idx - 2560) >> 9;
            const int row = (f >> 1) * 16 + c16, k = (f & 1) * 32 + kloc;
            if (row < 36) v = (k < 36) ? w3[row * 36 + k] : (k == 36 ? b3[row] : 0.0f);
        } else {                                // A4 [kt]
            const int row = c16, k = ((idx - 5632) >> 9) * 32 + kloc;
            if (row == 0) v = (k < 36) ? w4[k] : (k == 36 ? b4[0] : 0.0f);
        }
        const unsigned b = __float_as_uint(v);  // f32 -> bf16 RNE
        wp[idx] = (unsigned short)((b + 0x7FFFu + ((b >> 16) & 1u)) >> 16);
    }
}

// ---------------------------------------------------------------------------
// Kernel A v6 (R9): MFMA. R8 closed the VALU chapter: 86us / 38% VALUBusy /
// MfmaUtil 0 was invariant to atomics, stores, occupancy, block shape ->
// structural. Per wave, 64 points = X[4][64]; all 4 layers = 52 mfma
// (16x16x32 bf16) ~ 260 cyc vs ~2620 VALU cyc. Inter-layer C/D->B
// redistribution in-register: C/D row=(l>>4)*4+reg, col=(l&15) [HW-verified]
// -> B k=(l>>4)*8+j via ds_bpermute (srcl = c16+16*((R&7)>>1), parity p&1,
// mt select 4g+p<8), ~140 bperm/body. Biases ride as K-row (act row K == 1).
// Precision: bf16 inputs, f32 accum -> ~2-3e-3 abs err << 2e-2 threshold.
// Scatter/dedup path unchanged (R4-verified).
// ---------------------------------------------------------------------------
__global__ void __launch_bounds__(256) mlp_scatter_kernel(
    const float* __restrict__ input,        // [4][N]
    const int* __restrict__ tindex,         // [N][2] int32 (row, col)
    const unsigned short* __restrict__ wp,  // packed bf16 fragments
    int* __restrict__ counts,               // [W]
    uint2* __restrict__ list,               // [W][maxk]
    int maxk)
{
    if (tindex[0] == -1) return;            // empty-branch

    const int l   = threadIdx.x & 63;
    const int wav = (blockIdx.x * 256 + threadIdx.x) >> 6;
    const int base = wav << 6;
    if (base >= N_PTS) return;              // whole-wave early out (N%64==0)
    const int i = base + l;
    const int c16 = l & 15, g = l >> 4;

    // scatter-slot atomic first; latency hides under the GEMMs
    const int2 hw = ((const int2*)tindex)[i];
    const int pos = atomicAdd(&counts[hw.y], 1);

    // weight fragments (L1/L2-resident after first waves; 16B/lane each)
    const bf16x8* __restrict__ wf = (const bf16x8*)wp;
    const bf16x8 A1_0 = wf[0 * 64 + l], A1_1 = wf[1 * 64 + l];
    const bf16x8 A2_0 = wf[2 * 64 + l], A2_1 = wf[3 * 64 + l], A2_2 = wf[4 * 64 + l];
    const bf16x8 A3_00 = wf[5 * 64 + l], A3_01 = wf[6 * 64 + l];
    const bf16x8 A3_10 = wf[7 * 64 + l], A3_11 = wf[8 * 64 + l];
    const bf16x8 A3_20 = wf[9 * 64 + l], A3_21 = wf[10 * 64 + l];
    const bf16x8 A4_0 = wf[11 * 64 + l], A4_1 = wf[12 * 64 + l];

    const f32x4 zf = {0.0f, 0.0f, 0.0f, 0.0f};

    // x: lane p holds point base+p; pack to bf16 pairs (k0,k1) (k2,k3)
    const float x0 = input[0 * N_PTS + i], x1 = input[1 * N_PTS + i];
    const float x2 = input[2 * N_PTS + i], x3 = input[3 * N_PTS + i];
    const unsigned xp01 = cvt_pk_bf16(x0, x1);
    const unsigned xp23 = cvt_pk_bf16(x2, x3);

    // ---- L1: H1[18][64] (+pad) = A1 . [x;1;0...] ----
    unsigned P1[4][2][2];
#pragma unroll
    for (int t = 0; t < 4; ++t) {
        const unsigned srcl = (unsigned)(16 * t + c16);
        const unsigned bx0 = bperm_u(srcl, xp01);
        const unsigned bx1 = bperm_u(srcl, xp23);
        const unsigned d0 = (g == 0) ? bx0 : 0u;
        const unsigned d1 = (g == 0) ? bx1 : 0u;
        const unsigned d2 = (g == 0) ? 0x3F80u : 0u;   // k=4 -> 1.0 (bias row)
        const bf16x8 B = mk_frag(d0, d1, d2, 0u);
        const f32x4 D0 = __builtin_amdgcn_mfma_f32_16x16x32_bf16(A1_0, B, zf, 0, 0, 0);
        const f32x4 D1 = __builtin_amdgcn_mfma_f32_16x16x32_bf16(A1_1, B, zf, 0, 0, 0);
        P1[t][0][0] = cvt_pk_bf16(fmaxf(D0.x, 0.f), fmaxf(D0.y, 0.f));
        P1[t][0][1] = cvt_pk_bf16(fmaxf(D0.z, 0.f), fmaxf(D0.w, 0.f));
        P1[t][1][0] = cvt_pk_bf16(fmaxf(D1.x, 0.f), fmaxf(D1.y, 0.f));
        P1[t][1][1] = cvt_pk_bf16(fmaxf(D1.z, 0.f), fmaxf(D1.w, 0.f));
    }

    // ---- L2: H2[36][64] = A2 . [H1;1] (K=19 pad 32) ----
    unsigned P2[4][3][2];
#pragma unroll
    for (int t = 0; t < 4; ++t) {
        unsigned d[4];
#pragma unroll
        for (int p = 0; p < 4; ++p) {
            const int Rl = (4 * g + p) & 7;
            const unsigned srcl = (unsigned)(c16 + 16 * (Rl >> 1));
            const unsigned lo = bperm_u(srcl, P1[t][0][p & 1]);
            const unsigned hi = bperm_u(srcl, P1[t][1][p & 1]);
            d[p] = (4 * g + p < 8) ? lo : hi;
        }
        if (g == 2) d[1] = (d[1] & 0xFFFF0000u) | 0x3F80u;   // act row 18 = 1.0
        const bf16x8 B = mk_frag(d[0], d[1], d[2], d[3]);
        const f32x4 D0 = __builtin_amdgcn_mfma_f32_16x16x32_bf16(A2_0, B, zf, 0, 0, 0);
        const f32x4 D1 = __builtin_amdgcn_mfma_f32_16x16x32_bf16(A2_1, B, zf, 0, 0, 0);
        const f32x4 D2 = __builtin_amdgcn_mfma_f32_16x16x32_bf16(A2_2, B, zf, 0, 0, 0);
        P2[t][0][0] = cvt_pk_bf16(fmaxf(D0.x, 0.f), fmaxf(D0.y, 0.f));
        P2[t][0][1] = cvt_pk_bf16(fmaxf(D0.z, 0.f), fmaxf(D0.w, 0.f));
        P2[t][1][0] = cvt_pk_bf16(fmaxf(D1.x, 0.f), fmaxf(D1.y, 0.f));
        P2[t][1][1] = cvt_pk_bf16(fmaxf(D1.z, 0.f), fmaxf(D1.w, 0.f));
        P2[t][2][0] = cvt_pk_bf16(fmaxf(D2.x, 0.f), fmaxf(D2.y, 0.f));
        P2[t][2][1] = cvt_pk_bf16(fmaxf(D2.z, 0.f), fmaxf(D2.w, 0.f));
    }

    // ---- L3: H3[36][64] = A3 . [H2;1] (K=37 pad 64, 2 K-tiles) ----
    unsigned P3[4][3][2];
#pragma unroll
    for (int t = 0; t < 4; ++t) {
        unsigned dk0[4], dk1[4];
#pragma unroll
        for (int p = 0; p < 4; ++p) {
            const int Rl = (4 * g + p) & 7;
            const unsigned srcl = (unsigned)(c16 + 16 * (Rl >> 1));
            const unsigned lo = bperm_u(srcl, P2[t][0][p & 1]);
            const unsigned hi = bperm_u(srcl, P2[t][1][p & 1]);
            const unsigned m2 = bperm_u(srcl, P2[t][2][p & 1]);
            dk0[p] = (4 * g + p < 8) ? lo : hi;
            dk1[p] = (4 * g + p < 8) ? m2 : 0u;     // rows 48..63 = 0
        }
        if (g == 0) dk1[2] = (dk1[2] & 0xFFFF0000u) | 0x3F80u;  // act row 36 = 1.0
        const bf16x8 B0 = mk_frag(dk0[0], dk0[1], dk0[2], dk0[3]);
        const bf16x8 B1 = mk_frag(dk1[0], dk1[1], dk1[2], dk1[3]);
        f32x4 D0 = __builtin_amdgcn_mfma_f32_16x16x32_bf16(A3_00, B0, zf, 0, 0, 0);
        D0 = __builtin_amdgcn_mfma_f32_16x16x32_bf16(A3_01, B1, D0, 0, 0, 0);
        f32x4 D1 = __builtin_amdgcn_mfma_f32_16x16x32_bf16(A3_10, B0, zf, 0, 0, 0);
        D1 = __builtin_amdgcn_mfma_f32_16x16x32_bf16(A3_11, B1, D1, 0, 0, 0);
        f32x4 D2 = __builtin_amdgcn_mfma_f32_16x16x32_bf16(A3_20, B0, zf, 0, 0, 0);
        D2 = __builtin_amdgcn_mfma_f32_16x16x32_bf16(A3_21, B1, D2, 0, 0, 0);
        P3[t][0][0] = cvt_pk_bf16(fmaxf(D0.x, 0.f), fmaxf(D0.y, 0.f));
        P3[t][0][1] = cvt_pk_bf16(fmaxf(D0.z, 0.f), fmaxf(D0.w, 0.f));
        P3[t][1][0] = cvt_pk_bf16(fmaxf(D1.x, 0.f), fmaxf(D1.y, 0.f));
        P3[t][1][1] = cvt_pk_bf16(fmaxf(D1.z, 0.f), fmaxf(D1.w, 0.f));
        P3[t][2][0] = cvt_pk_bf16(fmaxf(D2.x, 0.f), fmaxf(D2.y, 0.f));
        P3[t][2][1] = cvt_pk_bf16(fmaxf(D2.z, 0.f), fmaxf(D2.w, 0.f));
    }

    // ---- L4: out[1][64] = A4 . [H3;1] ----
    float vout[4];
#pragma unroll
    for (int t = 0; t < 4; ++t) {
        unsigned dk0[4], dk1[4];
#pragma unroll
        for (int p = 0; p < 4; ++p) {
            const int Rl = (4 * g + p) & 7;
            const unsigned srcl = (unsigned)(c16 + 16 * (Rl >> 1));
            const unsigned lo = bperm_u(srcl, P3[t][0][p & 1]);
            const unsigned hi = bperm_u(srcl, P3[t][1][p & 1]);
            const unsigned m2 = bperm_u(srcl, P3[t][2][p & 1]);
            dk0[p] = (4 * g + p < 8) ? lo : hi;
            dk1[p] = (4 * g + p < 8) ? m2 : 0u;
        }
        if (g == 0) dk1[2] = (dk1[2] & 0xFFFF0000u) | 0x3F80u;  // act row 36 = 1.0
        const bf16x8 B0 = mk_frag(dk0[0], dk0[1], dk0[2], dk0[3]);
        const bf16x8 B1 = mk_frag(dk1[0], dk1[1], dk1[2], dk1[3]);
        f32x4 D = __builtin_amdgcn_mfma_f32_16x16x32_bf16(A4_0, B0, zf, 0, 0, 0);
        D = __builtin_amdgcn_mfma_f32_16x16x32_bf16(A4_1, B1, D, 0, 0, 0);
        vout[t] = D.x;                       // row 0 lives in lanes g==0, reg 0
    }

    // redistribute: point p's value sits in lane (p&15) of tile (p>>4)
    const unsigned r0 = bperm_u((unsigned)c16, __float_as_uint(vout[0]));
    const unsigned r1 = bperm_u((unsigned)c16, __float_as_uint(vout[1]));
    const unsigned r2 = bperm_u((unsigned)c16, __float_as_uint(vout[2]));
    const unsigned r3 = bperm_u((unsigned)c16, __float_as_uint(vout[3]));
    const unsigned vr = (g < 2) ? ((g == 0) ? r0 : r1) : ((g == 2) ? r2 : r3);

    if (pos < maxk) {   // never overflows statistically at maxk>=48
        uint2 e;
        e.x = vr;
        e.y = ((unsigned)i << 8) | (unsigned)hw.x;
        list[(size_t)hw.y * maxk + pos] = e;
    }
}

// Wave-local LDS ordering (colmax): drain this wave's DS ops.
__device__ __forceinline__ void lds_wave_fence() {
    asm volatile("s_waitcnt lgkmcnt(0)" ::: "memory");
}

// ---------------------------------------------------------------------------
// Kernel B (exact R4-verified version, passed R4/R8): 32-bit dedup keys,
// native ds_max_u32, grid-stride 2200 blocks x 4 waves x 8 cols.
// ---------------------------------------------------------------------------
__global__ void __launch_bounds__(256) colmax_kernel(
    const int* __restrict__ tindex,
    const int* __restrict__ counts,
    const uint2* __restrict__ list,
    float* __restrict__ out,
    int maxk)
{
    __shared__ unsigned rowwin[4][200];
    const int lane = threadIdx.x;        // 0..63
    const int y    = threadIdx.y;        // 0..3
    unsigned* tbl = rowwin[y];

    const bool empty = (tindex[0] == -1);

    if (blockIdx.x == 0 && lane == 0 && y == 0)
        out[W_DIM] = empty ? 0.0f : 1.0f;    // flag output

    tbl[lane]       = 0u;
    tbl[lane + 64]  = 0u;
    tbl[lane + 128] = 0u;
    if (lane < 8) tbl[lane + 192] = 0u;
    lds_wave_fence();

    const int step = gridDim.x * 4;
    for (int w = blockIdx.x * 4 + y; w < W_DIM; w += step) {
        int c = 0;
        if (!empty) {
            c = counts[w];
            if (c > maxk) c = maxk;
        }

        uint2 e = make_uint2(0u, 0u);
        const bool have = (lane < c);
        float v = FILL_V;
        if (have) {
            e = list[(size_t)w * maxk + lane];
            atomicMax(&tbl[e.y & 0xFFu], e.y);   // native ds_max_u32
        }
        lds_wave_fence();
        if (have) {
            if (tbl[e.y & 0xFFu] == e.y)
                v = __uint_as_float(e.x);
            tbl[e.y & 0xFFu] = 0u;
        }
        lds_wave_fence();

#pragma unroll
        for (int off = 32; off > 0; off >>= 1)
            v = fmaxf(v, __shfl_down(v, off, 64));

        if (lane == 0) out[w] = v;
    }
}

extern "C" void kernel_launch(void* const* d_in, const int* in_sizes, int n_in,
                              void* d_out, int out_size, void* d_ws, size_t ws_size,
                              hipStream_t stream) {
    const float* input  = (const float*)d_in[0];
    const int*   tindex = (const int*)d_in[1];   // int32 on device
    const float* w1 = (const float*)d_in[2];
    const float* b1 = (const float*)d_in[3];
    const float* w2 = (const float*)d_in[4];
    const float* b2 = (const float*)d_in[5];
    const float* w3 = (const float*)d_in[6];
    const float* b3 = (const float*)d_in[7];
    const float* w4 = (const float*)d_in[8];
    const float* b4 = (const float*)d_in[9];
    float* out = (float*)d_out;

    int*            counts = (int*)d_ws;
    unsigned short* wpack  = (unsigned short*)((char*)d_ws + COUNTS_BYTES);
    uint2*          list   = (uint2*)((char*)d_ws + COUNTS_BYTES + WPACK_BYTES);

    size_t head = COUNTS_BYTES + WPACK_BYTES;
    size_t avail = (ws_size > head) ? ws_size - head : 0;
    int maxk = (int)(avail / ((size_t)W_DIM * sizeof(uint2)));
    if (maxk > 64) maxk = 64;
    if (maxk < 1)  maxk = 1;

    (void)hipMemsetAsync(counts, 0, COUNTS_BYTES, stream);

    pack_weights_kernel<<<1, 256, 0, stream>>>(w1, b1, w2, b2, w3, b3, w4, b4, wpack);

    // 1e6/64 = 15625 waves, 4 waves/block -> 3907 blocks
    mlp_scatter_kernel<<<(N_PTS / 64 + 3) / 4, 256, 0, stream>>>(
        input, tindex, wpack, counts, list, maxk);

    colmax_kernel<<<2200, dim3(64, 4), 0, stream>>>(
        tindex, counts, list, out, maxk);
}